// Round 11
// baseline (372.754 us; speedup 1.0000x reference)
//
#include <hip/hip_runtime.h>
#include <hip/hip_bf16.h>

typedef _Float16 half8 __attribute__((ext_vector_type(8)));
typedef _Float16 half4v __attribute__((ext_vector_type(4)));
typedef float floatx4 __attribute__((ext_vector_type(4)));

#define C_DIM 256
#define M_DIM 512
#define HW 4096
#define TAU 0.0025f
#define LCAP 96
#define NZERO 512   // blocks that own a zero-fill chunk (= one residency round)

// ---------------- prep: memN = l2norm(relu(relu(mem@w1+b1)@w2+b2)) ----------------
// Zero-fill of att_map moved INTO main (gated); prep only inits the sync counters.
__global__ __launch_bounds__(128) void prep_kernel(
    const float* __restrict__ memory, const float* __restrict__ w1,
    const float* __restrict__ b1, const float* __restrict__ w2,
    const float* __restrict__ b2,
    _Float16* __restrict__ mN, float* __restrict__ mN32,
    int* __restrict__ sync)
{
  __shared__ float sm[256];
  __shared__ float sh[128];
  __shared__ float s_part[2];
  __shared__ float s_tot;
  const int r = blockIdx.x;
  const int t = threadIdx.x;
  if (r == 0 && t == 0) { sync[0] = 0; sync[32] = 0; }  // ticket ctr, done ctr

  sm[t]       = memory[r * C_DIM + t];
  sm[t + 128] = memory[r * C_DIM + t + 128];
  __syncthreads();
  float acc = b1[t];
#pragma unroll 8
  for (int c = 0; c < 256; ++c) acc = fmaf(sm[c], w1[c * 128 + t], acc);
  sh[t] = fmaxf(acc, 0.f);
  __syncthreads();
  float o0 = b2[t], o1 = b2[t + 128];
#pragma unroll 8
  for (int k = 0; k < 128; ++k) {
    float h = sh[k];
    o0 = fmaf(h, w2[k * 256 + t], o0);
    o1 = fmaf(h, w2[k * 256 + t + 128], o1);
  }
  o0 = fmaxf(o0, 0.f);
  o1 = fmaxf(o1, 0.f);
  float ss = o0 * o0 + o1 * o1;
#pragma unroll
  for (int off = 32; off >= 1; off >>= 1) ss += __shfl_down(ss, off);
  if ((t & 63) == 0) s_part[t >> 6] = ss;
  __syncthreads();
  if (t == 0) s_tot = s_part[0] + s_part[1];
  __syncthreads();
  const float inv = 1.f / fmaxf(sqrtf(s_tot), 1e-12f);
  const float v0 = o0 * inv, v1 = o1 * inv;
  mN[r * C_DIM + t]        = (_Float16)v0;
  mN[r * C_DIM + t + 128]  = (_Float16)v1;
  mN32[r * C_DIM + t]       = v0;
  mN32[r * C_DIM + t + 128] = v1;
}

#define MFMA16(a, b, c) __builtin_amdgcn_mfma_f32_16x16x32_f16(a, b, c, 0, 0, 0)

// ---------------- fused main kernel: 64 pixels per block, 1024 blocks ----------------
// R10 structure + in-kernel gated zero-fill of att_map:
//  * First NZERO arriving blocks (atomic ticket) each zero a contiguous 256 KB chunk.
//    Stores are issued in the GEMM1->PhaseC window (no vmem there otherwise) and drain
//    at B2's natural vmcnt(0) -- the zero stream rides inside existing stall windows
//    instead of a serial 20 us pre-pass (R10 prep).
//  * Release: after B2 all 8 waves' zero stores are retired; tid0 __threadfence()
//    (device-scope, flushes XCD L2) then done++. Acquire: before the sparse scatter,
//    lane 0 of each wave spins on done==NZERO (device atomic), __shfl broadcast --
//    per-wave gate, NO post-store __syncthreads (R5/R6 drain trap avoided).
//  * Sparse att values scatter at the very END from the LDS lists (they persist),
//    after the out-gather loads and out stores (loads-before-stores, R6 lesson).
//  * No dispatch-order assumption: tickets go to whoever arrives first; every ticket
//    holder increments done unconditionally -> no deadlock (G16-safe).
__global__ __launch_bounds__(512, 4) void main_kernel(
    const float* __restrict__ x,
    const _Float16* __restrict__ mN,
    const float* __restrict__ mN32,
    float* __restrict__ out, float* __restrict__ attmap,
    int* __restrict__ sync)
{
  __shared__ _Float16       Xh[64][264];      // 33792 B
  __shared__ unsigned short s_lslot[64][LCAP];// 12288 B
  __shared__ float          s_lval[64][LCAP]; // 24576 B
  __shared__ int      s_cnt[64];
  __shared__ float    s_sumsq[64];
  __shared__ float    s_sum1[64];
  __shared__ float    s_sum2[64];
  __shared__ int      s_ticket;

  const int tid  = threadIdx.x;
  const int wave = tid >> 6;     // 0..7
  const int lane = tid & 63;
  const int q    = lane >> 4;    // quad within wave
  const int c16  = lane & 15;
  const int g    = tid >> 3;     // 0..63: channel quad for phase A
  const int pxq  = tid & 7;      // pixel quad (with half-loop) for phase A

  const int blk = blockIdx.x;          // 1024 blocks
  const int img = blk >> 6;            // 64 blocks per image
  const int hw0 = (blk & 63) * 64;
  const float* __restrict__ xb = x + (size_t)img * C_DIM * HW + hw0;

  if (tid == 0) s_ticket = atomicAdd(&sync[0], 1);
  if (tid < 64) {
    s_sumsq[tid] = 0.f; s_sum1[tid] = 0.f; s_sum2[tid] = 0.f; s_cnt[tid] = 0;
  }
  __syncthreads();  // B0
  const int ticket = s_ticket;

  // ---- Phase A: float4 loads (2 halves x 4 ch x 4 px per thread), fp16 pack, sumsq
#pragma unroll
  for (int h = 0; h < 2; ++h) {
    floatx4 v[4];
#pragma unroll
    for (int i = 0; i < 4; ++i)
      v[i] = *(const floatx4*)(xb + (size_t)(4 * g + i) * HW + (pxq + 8 * h) * 4);
    float ps[4];
#pragma unroll
    for (int j = 0; j < 4; ++j) {
      const int p = (pxq + 8 * h) * 4 + j;
      half4v hv = {(_Float16)v[0][j], (_Float16)v[1][j], (_Float16)v[2][j], (_Float16)v[3][j]};
      *(half4v*)&Xh[p][4 * g] = hv;
      ps[j] = v[0][j] * v[0][j] + v[1][j] * v[1][j] + v[2][j] * v[2][j] + v[3][j] * v[3][j];
    }
#pragma unroll
    for (int off = 8; off < 64; off <<= 1)
#pragma unroll
      for (int j = 0; j < 4; ++j) ps[j] += __shfl_xor(ps[j], off);
    if ((lane >> 3) == 0) {
#pragma unroll
      for (int j = 0; j < 4; ++j) atomicAdd(&s_sumsq[4 * (lane & 7) + 32 * h + j], ps[j]);
    }
  }

  // GEMM1 initial B prefetch before the barrier: L2 latency hides in barrier wait
  const _Float16* bp[4];
#pragma unroll
  for (int nt = 0; nt < 4; ++nt)
    bp[nt] = mN + (size_t)(wave * 64 + nt * 16 + c16) * C_DIM + q * 8;
  half8 bcur[4], bnxt[4];
#pragma unroll
  for (int nt = 0; nt < 4; ++nt) bcur[nt] = *(const half8*)bp[nt];

  __syncthreads();  // B1: Xh + sumsq ready

  // ---- Phase B: GEMM1  S[64][512] = Xh @ mN^T  (fp16 MFMA, 2-stage B prefetch)
  floatx4 acc[4][4];
#pragma unroll
  for (int mt = 0; mt < 4; ++mt)
#pragma unroll
    for (int nt = 0; nt < 4; ++nt) {
      floatx4 z = {0.f, 0.f, 0.f, 0.f};
      acc[mt][nt] = z;
    }
#pragma unroll
  for (int kb = 0; kb < 8; ++kb) {
    if (kb < 7) {
#pragma unroll
      for (int nt = 0; nt < 4; ++nt) bnxt[nt] = *(const half8*)(bp[nt] + (kb + 1) * 32);
    }
    const int k0 = kb * 32 + q * 8;
    half8 ah[4];
#pragma unroll
    for (int mt = 0; mt < 4; ++mt) ah[mt] = *(const half8*)&Xh[mt * 16 + c16][k0];
#pragma unroll
    for (int nt = 0; nt < 4; ++nt)
#pragma unroll
      for (int mt = 0; mt < 4; ++mt)
        acc[mt][nt] = MFMA16(ah[mt], bcur[nt], acc[mt][nt]);
#pragma unroll
    for (int nt = 0; nt < 4; ++nt) bcur[nt] = bnxt[nt];
  }

  // ---- gated zero-fill: issue AFTER all GEMM vmem loads (younger stores never
  //      block older loads), drain at B2's implicit vmcnt(0) where waves stall anyway.
  if (ticket < NZERO) {
    floatx4* dst = (floatx4*)attmap + (size_t)ticket * 16384 + tid;
    const floatx4 z = {0.f, 0.f, 0.f, 0.f};
#pragma unroll
    for (int k = 0; k < 32; ++k) { *dst = z; dst += 512; }
  }

  // ---- Phase C: scale by 1/||x||, exp (cosines in [-1,1], no max shift needed)
  // C/D layout: value (m = mt*16 + q*4 + r, n = wave*64 + nt*16 + c16)
#pragma unroll
  for (int mt = 0; mt < 4; ++mt)
#pragma unroll
    for (int r = 0; r < 4; ++r) {
      const int m = mt * 16 + q * 4 + r;
      const float iv = 1.f / fmaxf(sqrtf(s_sumsq[m]), 1e-12f);
      float s = 0.f;
#pragma unroll
      for (int nt = 0; nt < 4; ++nt) {
        const float e = __expf(acc[mt][nt][r] * iv);
        acc[mt][nt][r] = e;
        s += e;
      }
      s += __shfl_xor(s, 1);
      s += __shfl_xor(s, 2);
      s += __shfl_xor(s, 4);
      s += __shfl_xor(s, 8);
      if (c16 == 0) atomicAdd(&s_sum1[m], s);
    }
  __syncthreads();  // B2: denominators ready; ALL waves' zero stores retired here

  // release: zeros of this block are globally visible after fence; signal done
  if (ticket < NZERO && tid == 0) {
    __threadfence();
    atomicAdd(&sync[32], 1);
  }

  // t = relu(p - tau); row sum of t
#pragma unroll
  for (int mt = 0; mt < 4; ++mt)
#pragma unroll
    for (int r = 0; r < 4; ++r) {
      const int m = mt * 16 + q * 4 + r;
      const float isum = 1.f / s_sum1[m];
      float s = 0.f;
#pragma unroll
      for (int nt = 0; nt < 4; ++nt) {
        const float tv = fmaxf(acc[mt][nt][r] * isum - TAU, 0.f);
        acc[mt][nt][r] = tv;
        s += tv;
      }
      s += __shfl_xor(s, 1);
      s += __shfl_xor(s, 2);
      s += __shfl_xor(s, 4);
      s += __shfl_xor(s, 8);
      if (c16 == 0) atomicAdd(&s_sum2[m], s);
    }
  __syncthreads();  // B3: shrink sums ready

  // ---- normalize att in regs; emit nonzeros to per-pixel lists (scatter deferred)
#pragma unroll
  for (int mt = 0; mt < 4; ++mt) {
    float rs[4];
#pragma unroll
    for (int r = 0; r < 4; ++r)
      rs[r] = 1.f / fmaxf(s_sum2[mt * 16 + q * 4 + r], 1e-12f);
#pragma unroll
    for (int nt = 0; nt < 4; ++nt) {
      floatx4 a4 = acc[mt][nt];
      const unsigned n = wave * 64 + nt * 16 + c16;
#pragma unroll
      for (int r = 0; r < 4; ++r) {
        a4[r] *= rs[r];
        if (a4[r] > 0.f) {
          const int m = mt * 16 + q * 4 + r;
          const int idx = atomicAdd(&s_cnt[m], 1);
          if (idx < LCAP) {
            s_lslot[m][idx] = (unsigned short)n;
            s_lval[m][idx]  = a4[r];
          }
        }
      }
    }
  }
  __syncthreads();  // B4: lists ready (LAST barrier)

  // ---- sparse gather: thread owns 4 consecutive pixels x 8 channels.
  const int px4 = (tid & 15) * 4;   // pixels px4..px4+3
  const int chg = tid >> 4;         // 0..31 -> channels [8*chg, 8*chg+8)
  floatx4 f[8] = {{0.f,0.f,0.f,0.f},{0.f,0.f,0.f,0.f},{0.f,0.f,0.f,0.f},{0.f,0.f,0.f,0.f},
                  {0.f,0.f,0.f,0.f},{0.f,0.f,0.f,0.f},{0.f,0.f,0.f,0.f},{0.f,0.f,0.f,0.f}};
#pragma unroll
  for (int p = 0; p < 4; ++p) {
    const int cn = min(s_cnt[px4 + p], LCAP);
    for (int j = 0; j < cn; ++j) {
      const int slot  = s_lslot[px4 + p][j];
      const float v   = s_lval[px4 + p][j];
      const floatx4* row = (const floatx4*)(mN32 + (size_t)slot * C_DIM + chg * 8);
      const floatx4 r0 = row[0], r1 = row[1];
      f[0][p] += v * r0[0]; f[1][p] += v * r0[1];
      f[2][p] += v * r0[2]; f[3][p] += v * r0[3];
      f[4][p] += v * r1[0]; f[5][p] += v * r1[1];
      f[6][p] += v * r1[2]; f[7][p] += v * r1[3];
    }
  }

  // ---- out stores: float4 per (channel, 4-px group); 16 lanes x 16 B = 256 B/instr
#pragma unroll
  for (int c = 0; c < 8; ++c)
    *(floatx4*)(out + ((size_t)img * C_DIM + chg * 8 + c) * HW + hw0 + px4) = f[c];

  // ---- acquire gate (per-wave, no barrier): wait until all NZERO chunks are zeroed,
  //      then scatter this block's sparse att values from the LDS lists.
  int gate = 0;
  if (lane == 0) {
    while (atomicAdd(&sync[32], 0) < NZERO) __builtin_amdgcn_s_sleep(8);
    gate = 1;
  }
  gate = __shfl(gate, 0);
  if (gate) {
    // wave w handles pixels [w*8, w*8+8); lane l: px offset l>>3, entries j = (l&7)+8k
    const int px = wave * 8 + (lane >> 3);
    const int cn = min(s_cnt[px], LCAP);
    for (int j = (lane & 7); j < cn; j += 8) {
      const int slot = s_lslot[px][j];
      attmap[((size_t)img * M_DIM + slot) * HW + hw0 + px] = s_lval[px][j];
    }
  }
}

extern "C" void kernel_launch(void* const* d_in, const int* in_sizes, int n_in,
                              void* d_out, int out_size, void* d_ws, size_t ws_size,
                              hipStream_t stream) {
  (void)in_sizes; (void)n_in; (void)out_size; (void)ws_size;
  const float* x      = (const float*)d_in[0];
  const float* memory = (const float*)d_in[1];
  const float* w1     = (const float*)d_in[2];
  const float* b1     = (const float*)d_in[3];
  const float* w2     = (const float*)d_in[4];
  const float* b2     = (const float*)d_in[5];
  float* out    = (float*)d_out;
  float* attmap = out + (size_t)16 * C_DIM * HW;  // output first, att_map second

  _Float16* mN   = (_Float16*)d_ws;
  float*    mN32 = (float*)((char*)d_ws + (size_t)M_DIM * C_DIM * sizeof(_Float16));
  int*      sync = (int*)((char*)d_ws + (size_t)M_DIM * C_DIM * 6);  // after mN+mN32

  hipLaunchKernelGGL(prep_kernel, dim3(M_DIM), dim3(128), 0, stream,
                     memory, w1, b1, w2, b2, mN, mN32, sync);
  hipLaunchKernelGGL(main_kernel, dim3(1024), dim3(512), 0, stream,
                     x, mN, mN32, out, attmap, sync);
}

// Round 13
// 325.906 us; speedup vs baseline: 1.1437x; 1.1437x over previous
//
#include <hip/hip_runtime.h>
#include <hip/hip_bf16.h>

typedef _Float16 half8 __attribute__((ext_vector_type(8)));
typedef _Float16 half4v __attribute__((ext_vector_type(4)));
typedef float floatx4 __attribute__((ext_vector_type(4)));

#define C_DIM 256
#define M_DIM 512
#define HW 4096
#define TAU 0.0025f
#define LCAP 96

// ---------------- prep: memN = l2norm(relu(relu(mem@w1+b1)@w2+b2)) ----------------
// Also zero-fills att_map (134 MB, contiguous, ~21 us BW-bound) fused here so the
// MLP VALU work rides under the write stream and we save one kernel launch.
// (R11 post-mortem: do NOT try to overlap this inside main_kernel — __syncthreads'
// vmcnt(0) drain puts the zero stream on every block's critical path.)
__global__ __launch_bounds__(128) void prep_kernel(
    const float* __restrict__ memory, const float* __restrict__ w1,
    const float* __restrict__ b1, const float* __restrict__ w2,
    const float* __restrict__ b2,
    _Float16* __restrict__ mN, float* __restrict__ mN32,
    float* __restrict__ attmap)
{
  __shared__ float sm[256];
  __shared__ float sh[128];
  __shared__ float s_part[2];
  __shared__ float s_tot;
  const int r = blockIdx.x;
  const int t = threadIdx.x;

  // ---- att_map zero-fill: 512 blocks x 128 thr, 128 float4 each, coalesced
  {
    const floatx4 z = {0.f, 0.f, 0.f, 0.f};
    floatx4* p4 = (floatx4*)attmap;
    size_t i = (size_t)r * 128 + t;           // 65536 threads
#pragma unroll 4
    for (int k = 0; k < 128; ++k) { p4[i] = z; i += 65536; }
  }

  sm[t]       = memory[r * C_DIM + t];
  sm[t + 128] = memory[r * C_DIM + t + 128];
  __syncthreads();
  float acc = b1[t];
#pragma unroll 8
  for (int c = 0; c < 256; ++c) acc = fmaf(sm[c], w1[c * 128 + t], acc);
  sh[t] = fmaxf(acc, 0.f);
  __syncthreads();
  float o0 = b2[t], o1 = b2[t + 128];
#pragma unroll 8
  for (int k = 0; k < 128; ++k) {
    float h = sh[k];
    o0 = fmaf(h, w2[k * 256 + t], o0);
    o1 = fmaf(h, w2[k * 256 + t + 128], o1);
  }
  o0 = fmaxf(o0, 0.f);
  o1 = fmaxf(o1, 0.f);
  float ss = o0 * o0 + o1 * o1;
#pragma unroll
  for (int off = 32; off >= 1; off >>= 1) ss += __shfl_down(ss, off);
  if ((t & 63) == 0) s_part[t >> 6] = ss;
  __syncthreads();
  if (t == 0) s_tot = s_part[0] + s_part[1];
  __syncthreads();
  const float inv = 1.f / fmaxf(sqrtf(s_tot), 1e-12f);
  const float v0 = o0 * inv, v1 = o1 * inv;
  mN[r * C_DIM + t]        = (_Float16)v0;
  mN[r * C_DIM + t + 128]  = (_Float16)v1;
  mN32[r * C_DIM + t]       = v0;
  mN32[r * C_DIM + t + 128] = v1;
}

#define MFMA16(a, b, c) __builtin_amdgcn_mfma_f32_16x16x32_f16(a, b, c, 0, 0, 0)

// ---------------- fused main kernel: 64 pixels per block, 1024 blocks ----------------
// Proven best (R10): 64-px tile, 4x4 acc GEMM1 with live B-prefetch (VGPR 64 +
// 64 AGPR = the 2-blocks/CU register tier; 3 blocks/CU is arithmetically impossible
// with a 64-reg accumulator, so this is the occupancy/ILP optimum for this shape).
// att is ~99.99% zero -> sparse epilogue: inline fp32 scatter into pre-zeroed att_map,
// per-pixel LDS lists feed a 0-2 row gather for out. Out stores are 8x float4/thread.
__global__ __launch_bounds__(512, 4) void main_kernel(
    const float* __restrict__ x,
    const _Float16* __restrict__ mN,
    const float* __restrict__ mN32,
    float* __restrict__ out, float* __restrict__ attmap)
{
  __shared__ _Float16       Xh[64][264];      // 33792 B
  __shared__ unsigned short s_lslot[64][LCAP];// 12288 B
  __shared__ float          s_lval[64][LCAP]; // 24576 B
  __shared__ int      s_cnt[64];
  __shared__ float    s_sumsq[64];
  __shared__ float    s_sum1[64];
  __shared__ float    s_sum2[64];

  const int tid  = threadIdx.x;
  const int wave = tid >> 6;     // 0..7
  const int lane = tid & 63;
  const int q    = lane >> 4;    // quad within wave
  const int c16  = lane & 15;
  const int g    = tid >> 3;     // 0..63: channel quad for phase A
  const int pxq  = tid & 7;      // pixel quad (with half-loop) for phase A

  const int blk = blockIdx.x;          // 1024 blocks
  const int img = blk >> 6;            // 64 blocks per image
  const int hw0 = (blk & 63) * 64;
  const float* __restrict__ xb = x + (size_t)img * C_DIM * HW + hw0;

  if (tid < 64) {
    s_sumsq[tid] = 0.f; s_sum1[tid] = 0.f; s_sum2[tid] = 0.f; s_cnt[tid] = 0;
  }
  __syncthreads();  // B0

  // ---- Phase A: float4 loads (2 halves x 4 ch x 4 px per thread), fp16 pack, sumsq
#pragma unroll
  for (int h = 0; h < 2; ++h) {
    floatx4 v[4];
#pragma unroll
    for (int i = 0; i < 4; ++i)
      v[i] = *(const floatx4*)(xb + (size_t)(4 * g + i) * HW + (pxq + 8 * h) * 4);
    float ps[4];
#pragma unroll
    for (int j = 0; j < 4; ++j) {
      const int p = (pxq + 8 * h) * 4 + j;
      half4v hv = {(_Float16)v[0][j], (_Float16)v[1][j], (_Float16)v[2][j], (_Float16)v[3][j]};
      *(half4v*)&Xh[p][4 * g] = hv;
      ps[j] = v[0][j] * v[0][j] + v[1][j] * v[1][j] + v[2][j] * v[2][j] + v[3][j] * v[3][j];
    }
#pragma unroll
    for (int off = 8; off < 64; off <<= 1)
#pragma unroll
      for (int j = 0; j < 4; ++j) ps[j] += __shfl_xor(ps[j], off);
    if ((lane >> 3) == 0) {
#pragma unroll
      for (int j = 0; j < 4; ++j) atomicAdd(&s_sumsq[4 * (lane & 7) + 32 * h + j], ps[j]);
    }
  }

  // GEMM1 initial B prefetch before the barrier: L2 latency hides in barrier wait
  const _Float16* bp[4];
#pragma unroll
  for (int nt = 0; nt < 4; ++nt)
    bp[nt] = mN + (size_t)(wave * 64 + nt * 16 + c16) * C_DIM + q * 8;
  half8 bcur[4], bnxt[4];
#pragma unroll
  for (int nt = 0; nt < 4; ++nt) bcur[nt] = *(const half8*)bp[nt];

  __syncthreads();  // B1: Xh + sumsq ready

  // ---- Phase B: GEMM1  S[64][512] = Xh @ mN^T  (fp16 MFMA, 2-stage B prefetch)
  floatx4 acc[4][4];
#pragma unroll
  for (int mt = 0; mt < 4; ++mt)
#pragma unroll
    for (int nt = 0; nt < 4; ++nt) {
      floatx4 z = {0.f, 0.f, 0.f, 0.f};
      acc[mt][nt] = z;
    }
#pragma unroll
  for (int kb = 0; kb < 8; ++kb) {
    if (kb < 7) {
#pragma unroll
      for (int nt = 0; nt < 4; ++nt) bnxt[nt] = *(const half8*)(bp[nt] + (kb + 1) * 32);
    }
    const int k0 = kb * 32 + q * 8;
    half8 ah[4];
#pragma unroll
    for (int mt = 0; mt < 4; ++mt) ah[mt] = *(const half8*)&Xh[mt * 16 + c16][k0];
#pragma unroll
    for (int nt = 0; nt < 4; ++nt)
#pragma unroll
      for (int mt = 0; mt < 4; ++mt)
        acc[mt][nt] = MFMA16(ah[mt], bcur[nt], acc[mt][nt]);
#pragma unroll
    for (int nt = 0; nt < 4; ++nt) bcur[nt] = bnxt[nt];
  }

  // ---- Phase C: scale by 1/||x||, exp (cosines in [-1,1], no max shift needed)
  // C/D layout: value (m = mt*16 + q*4 + r, n = wave*64 + nt*16 + c16)
#pragma unroll
  for (int mt = 0; mt < 4; ++mt)
#pragma unroll
    for (int r = 0; r < 4; ++r) {
      const int m = mt * 16 + q * 4 + r;
      const float iv = 1.f / fmaxf(sqrtf(s_sumsq[m]), 1e-12f);
      float s = 0.f;
#pragma unroll
      for (int nt = 0; nt < 4; ++nt) {
        const float e = __expf(acc[mt][nt][r] * iv);
        acc[mt][nt][r] = e;
        s += e;
      }
      s += __shfl_xor(s, 1);
      s += __shfl_xor(s, 2);
      s += __shfl_xor(s, 4);
      s += __shfl_xor(s, 8);
      if (c16 == 0) atomicAdd(&s_sum1[m], s);
    }
  __syncthreads();  // B2: softmax denominators ready

  // t = relu(p - tau); row sum of t
#pragma unroll
  for (int mt = 0; mt < 4; ++mt)
#pragma unroll
    for (int r = 0; r < 4; ++r) {
      const int m = mt * 16 + q * 4 + r;
      const float isum = 1.f / s_sum1[m];
      float s = 0.f;
#pragma unroll
      for (int nt = 0; nt < 4; ++nt) {
        const float tv = fmaxf(acc[mt][nt][r] * isum - TAU, 0.f);
        acc[mt][nt][r] = tv;
        s += tv;
      }
      s += __shfl_xor(s, 1);
      s += __shfl_xor(s, 2);
      s += __shfl_xor(s, 4);
      s += __shfl_xor(s, 8);
      if (c16 == 0) atomicAdd(&s_sum2[m], s);
    }
  __syncthreads();  // B3: shrink sums ready

  // ---- normalize att in regs; emit nonzeros to per-pixel lists AND scatter the
  //      (rare, ~0.045/lane) fp32 values straight into the pre-zeroed att_map.
#pragma unroll
  for (int mt = 0; mt < 4; ++mt) {
    float rs[4];
#pragma unroll
    for (int r = 0; r < 4; ++r)
      rs[r] = 1.f / fmaxf(s_sum2[mt * 16 + q * 4 + r], 1e-12f);
#pragma unroll
    for (int nt = 0; nt < 4; ++nt) {
      floatx4 a4 = acc[mt][nt];
      const unsigned n = wave * 64 + nt * 16 + c16;
#pragma unroll
      for (int r = 0; r < 4; ++r) {
        a4[r] *= rs[r];
        if (a4[r] > 0.f) {
          const int m = mt * 16 + q * 4 + r;
          const int idx = atomicAdd(&s_cnt[m], 1);
          if (idx < LCAP) {
            s_lslot[m][idx] = (unsigned short)n;
            s_lval[m][idx]  = a4[r];
          }
          attmap[((size_t)img * M_DIM + n) * HW + hw0 + m] = a4[r];
        }
      }
    }
  }
  __syncthreads();  // B4: lists ready (few outstanding stores -> cheap drain)

  // ---- sparse gather: thread owns 4 consecutive pixels x 8 channels.
  // All loads precede all stores (R6 lesson).
  const int px4 = (tid & 15) * 4;   // pixels px4..px4+3
  const int chg = tid >> 4;         // 0..31 -> channels [8*chg, 8*chg+8)
  floatx4 f[8] = {{0.f,0.f,0.f,0.f},{0.f,0.f,0.f,0.f},{0.f,0.f,0.f,0.f},{0.f,0.f,0.f,0.f},
                  {0.f,0.f,0.f,0.f},{0.f,0.f,0.f,0.f},{0.f,0.f,0.f,0.f},{0.f,0.f,0.f,0.f}};
#pragma unroll
  for (int p = 0; p < 4; ++p) {
    const int cn = min(s_cnt[px4 + p], LCAP);
    for (int j = 0; j < cn; ++j) {
      const int slot  = s_lslot[px4 + p][j];
      const float v   = s_lval[px4 + p][j];
      const floatx4* row = (const floatx4*)(mN32 + (size_t)slot * C_DIM + chg * 8);
      const floatx4 r0 = row[0], r1 = row[1];
      f[0][p] += v * r0[0]; f[1][p] += v * r0[1];
      f[2][p] += v * r0[2]; f[3][p] += v * r0[3];
      f[4][p] += v * r1[0]; f[5][p] += v * r1[1];
      f[6][p] += v * r1[2]; f[7][p] += v * r1[3];
    }
  }

  // ---- out stores: float4 per (channel, 4-px group); 16 lanes x 16 B = 256 B/instr
#pragma unroll
  for (int c = 0; c < 8; ++c)
    *(floatx4*)(out + ((size_t)img * C_DIM + chg * 8 + c) * HW + hw0 + px4) = f[c];
}

extern "C" void kernel_launch(void* const* d_in, const int* in_sizes, int n_in,
                              void* d_out, int out_size, void* d_ws, size_t ws_size,
                              hipStream_t stream) {
  (void)in_sizes; (void)n_in; (void)out_size; (void)ws_size;
  const float* x      = (const float*)d_in[0];
  const float* memory = (const float*)d_in[1];
  const float* w1     = (const float*)d_in[2];
  const float* b1     = (const float*)d_in[3];
  const float* w2     = (const float*)d_in[4];
  const float* b2     = (const float*)d_in[5];
  float* out    = (float*)d_out;
  float* attmap = out + (size_t)16 * C_DIM * HW;  // output first, att_map second

  _Float16* mN   = (_Float16*)d_ws;
  float*    mN32 = (float*)((char*)d_ws + (size_t)M_DIM * C_DIM * sizeof(_Float16));

  hipLaunchKernelGGL(prep_kernel, dim3(M_DIM), dim3(128), 0, stream,
                     memory, w1, b1, w2, b2, mN, mN32, attmap);
  hipLaunchKernelGGL(main_kernel, dim3(1024), dim3(512), 0, stream,
                     x, mN, mN32, out, attmap);
}